// Round 9
// baseline (157.344 us; speedup 1.0000x reference)
//
#include <hip/hip_runtime.h>
#include <hip/hip_fp16.h>
#include <math.h>

#define CC 64
#define KK 16
#define NNODES 15
#define DD 512      // input feature dim
#define MM 512      // output dim
#define NN 16384    // rows

// ---------------------------------------------------------------------------
// XLA/Eigen fast-tanh for f32 (bit-exact vs JAX's jnp.tanh lowering).
// Round 3/4/5 evidence: required to match the golden's argmax codes.
// ---------------------------------------------------------------------------
__device__ __forceinline__ float xla_tanhf(float x) {
    const float kMax = 7.90531110763549805f;
    bool tiny = fabsf(x) < 0.0004f;
    float xc = fminf(fmaxf(x, -kMax), kMax);
    float x2 = __fmul_rn(xc, xc);
    float p = __fmaf_rn(x2, -2.76076847742355e-16f, 2.00018790482477e-13f);
    p = __fmaf_rn(x2, p, -8.60467152213735e-11f);
    p = __fmaf_rn(x2, p, 5.12229709037114e-08f);
    p = __fmaf_rn(x2, p, 1.48572235717979e-05f);
    p = __fmaf_rn(x2, p, 6.37261928875436e-04f);
    p = __fmaf_rn(x2, p, 4.89352455891786e-03f);
    p = __fmul_rn(xc, p);
    float q = __fmaf_rn(x2, 1.19825839466702e-06f, 1.18534705686654e-04f);
    q = __fmaf_rn(x2, q, 2.26843463243900e-03f);
    q = __fmaf_rn(x2, q, 4.89352518554385e-03f);
    return tiny ? x : __fdiv_rn(p, q);
}

// ---------------------------------------------------------------------------
// Kernel 1: transpose — L (M, C*K) fp32 -> Lt16 (C*K, M) fp16 via LDS
// 64x64 tiles: coalesced reads AND coalesced 16B writes. (round-7 verified)
// ---------------------------------------------------------------------------
__global__ __launch_bounds__(256) void transpose_lut16(const float* __restrict__ L,
                                                       __half* __restrict__ Lt) {
    __shared__ __half tile[64 * 72];   // [ck_local][m_local], stride 72
    const int tid = threadIdx.x;
    const int ck0 = (blockIdx.x & 15) * 64;
    const int m0  = (blockIdx.x >> 4) * 64;

    const int col = tid & 63;
#pragma unroll
    for (int i = 0; i < 16; ++i) {
        int r = (tid >> 6) + i * 4;
        float v = L[(size_t)(m0 + r) * (CC * KK) + ck0 + col];
        tile[col * 72 + r] = __float2half(v);
    }
    __syncthreads();

#pragma unroll
    for (int t = 0; t < 2; ++t) {
        int cr   = (tid >> 3) + t * 32;
        int mseg = (tid & 7) * 8;
        uint4 v = *(const uint4*)&tile[cr * 72 + mseg];
        *(uint4*)(Lt + ((size_t)(ck0 + cr) * MM + m0 + mseg)) = v;
    }
}

// ---------------------------------------------------------------------------
// Kernel 2: FUSED encode+decode v2.
// Round-8 fixes:
//  (a) sA/sT stored TRANSPOSED ([sd][c], [i][c]) -> lane stride 1 -> zero
//      bank conflicts (was 64-lanes-one-bank, 3.67M conflict cycles).
//  (b) decode: codes pulled into 4 VGPR words once (no per-c ds_read_u8);
//      c-loop in groups of 4 with 4 independent acc sets -> >=4 outstanding
//      dwordx4 L2 loads (VGPR 32 -> ~80, latency hidden).
// ---------------------------------------------------------------------------
__global__ __launch_bounds__(256) void fused_kernel(const float* __restrict__ I,
                                                    const float* __restrict__ A,
                                                    const float* __restrict__ T,
                                                    const __half* __restrict__ Lt,
                                                    float* __restrict__ out) {
    __shared__ float sAT[32 * 64];     // [s*4+d][c]  (transposed, conflict-free)
    __shared__ float sTT[NNODES * 64]; // [i][c]      (transposed, conflict-free)
    __shared__ uint4 sIdxV[16];        // 4 rows x 64 codes, 16B-aligned
    unsigned char* sIdx = (unsigned char*)sIdxV;

    const int tid = threadIdx.x;
    for (int g = tid; g < 32 * 64; g += 256)      // sAT[sd*64+c] = A[c*32+sd]
        sAT[g] = A[((g & 63) << 5) + (g >> 6)];
    for (int g = tid; g < NNODES * 64; g += 256)  // sTT[i*64+c] = T[c*15+i]
        sTT[g] = T[(g & 63) * NNODES + (g >> 6)];
    __syncthreads();

    const int w    = tid >> 6;        // wave = local row
    const int lane = tid & 63;
    const int c    = lane;            // encode subspace
    const int j    = blockIdx.x * 4 + w;

    // ---------------- encode (bit-exact round-5 math) ----------------
    {
        const float* Ij = I + (size_t)j * DD + c * 8;   // wave reads 2KB contiguous
        float4 v0 = ((const float4*)Ij)[0];
        float4 v1 = ((const float4*)Ij)[1];
        float iv[8] = {v0.x, v0.y, v0.z, v0.w, v1.x, v1.y, v1.z, v1.w};

        float t[4] = {0.f, 0.f, 0.f, 0.f};
#pragma unroll
        for (int s = 0; s < 8; ++s) {
            float v = iv[s];
#pragma unroll
            for (int d = 0; d < 4; ++d)
                t[d] = __fmaf_rn(v, sAT[(s * 4 + d) * 64 + c], t[d]);
        }

        const int lvl[NNODES] = {0, 1, 1, 2, 2, 2, 2, 3, 3, 3, 3, 3, 3, 3, 3};
        float th[NNODES];
#pragma unroll
        for (int i = 0; i < NNODES; ++i) {
            float h = __fsub_rn(t[lvl[i]], sTT[i * 64 + c]);
            th[i] = xla_tanhf(h);
        }

        int best = 0;
        float bestv = -3.0e38f;
#pragma unroll
        for (int k = 0; k < KK; ++k) {
            int node = 0;
            float s = 0.f;
#pragma unroll
            for (int l = 0; l < 4; ++l) {
                int bit = (k >> (3 - l)) & 1;
                s = __fadd_rn(s, bit ? th[node] : -th[node]);
                node = 2 * node + 1 + bit;
            }
            if (s > bestv) { bestv = s; best = k; }   // strict >: first-max
        }
        sIdx[tid] = (unsigned char)best;
    }
    __syncthreads();

    // ---------------- decode: 4-way ILP over c ----------------
    const int m0 = lane * 8;          // 8 consecutive m per lane

    // all 64 codes of this row -> 4 registers (kills per-c LDS reads)
    const uint4 cv0 = sIdxV[w * 4 + 0];
    const uint4 cv1 = sIdxV[w * 4 + 1];
    const uint4 cv2 = sIdxV[w * 4 + 2];
    const uint4 cv3 = sIdxV[w * 4 + 3];
    unsigned int cws[16] = {cv0.x, cv0.y, cv0.z, cv0.w,
                            cv1.x, cv1.y, cv1.z, cv1.w,
                            cv2.x, cv2.y, cv2.z, cv2.w,
                            cv3.x, cv3.y, cv3.z, cv3.w};

    float acc0[8], acc1[8], acc2[8], acc3[8];
#pragma unroll
    for (int i = 0; i < 8; ++i) { acc0[i] = 0.f; acc1[i] = 0.f; acc2[i] = 0.f; acc3[i] = 0.f; }

    const __half* lt = Lt + m0;
#pragma unroll
    for (int g = 0; g < 16; ++g) {    // c = 4g..4g+3; 4 independent loads in flight
        unsigned int word = cws[g];
        const uint4 v0 = *(const uint4*)(lt + (size_t)(((4 * g + 0) << 4) + ( word        & 0xff)) * MM);
        const uint4 v1 = *(const uint4*)(lt + (size_t)(((4 * g + 1) << 4) + ((word >>  8) & 0xff)) * MM);
        const uint4 v2 = *(const uint4*)(lt + (size_t)(((4 * g + 2) << 4) + ((word >> 16) & 0xff)) * MM);
        const uint4 v3 = *(const uint4*)(lt + (size_t)(((4 * g + 3) << 4) + ( word >> 24        )) * MM);

        const unsigned int u0[4] = {v0.x, v0.y, v0.z, v0.w};
        const unsigned int u1[4] = {v1.x, v1.y, v1.z, v1.w};
        const unsigned int u2[4] = {v2.x, v2.y, v2.z, v2.w};
        const unsigned int u3[4] = {v3.x, v3.y, v3.z, v3.w};
#pragma unroll
        for (int q = 0; q < 4; ++q) {
            acc0[2 * q]     += __half2float(__ushort_as_half((unsigned short)(u0[q] & 0xffffu)));
            acc0[2 * q + 1] += __half2float(__ushort_as_half((unsigned short)(u0[q] >> 16)));
            acc1[2 * q]     += __half2float(__ushort_as_half((unsigned short)(u1[q] & 0xffffu)));
            acc1[2 * q + 1] += __half2float(__ushort_as_half((unsigned short)(u1[q] >> 16)));
            acc2[2 * q]     += __half2float(__ushort_as_half((unsigned short)(u2[q] & 0xffffu)));
            acc2[2 * q + 1] += __half2float(__ushort_as_half((unsigned short)(u2[q] >> 16)));
            acc3[2 * q]     += __half2float(__ushort_as_half((unsigned short)(u3[q] & 0xffffu)));
            acc3[2 * q + 1] += __half2float(__ushort_as_half((unsigned short)(u3[q] >> 16)));
        }
    }

    float res[8];
#pragma unroll
    for (int i = 0; i < 8; ++i)
        res[i] = __fadd_rn(__fadd_rn(__fadd_rn(acc0[i], acc1[i]), acc2[i]), acc3[i]);

    float* o = out + (size_t)j * MM + m0;
    *(float4*)(o)     = make_float4(res[0], res[1], res[2], res[3]);
    *(float4*)(o + 4) = make_float4(res[4], res[5], res[6], res[7]);
}

// ---------------------------------------------------------------------------
extern "C" void kernel_launch(void* const* d_in, const int* in_sizes, int n_in,
                              void* d_out, int out_size, void* d_ws, size_t ws_size,
                              hipStream_t stream) {
    const float* I = (const float*)d_in[0];  // (N, D) fp32
    const float* A = (const float*)d_in[1];  // (C, 8, 4) fp32
    const float* T = (const float*)d_in[2];  // (C*15,) fp32
    const float* L = (const float*)d_in[3];  // (M, C, K) fp32
    // d_in[4] = S, d_in[5] = B: structural constants, hard-coded.

    __half* Lt16 = (__half*)d_ws;            // 1 MB fp16 LUT
    float* out = (float*)d_out;              // (N, M) fp32

    hipLaunchKernelGGL(transpose_lut16, dim3(128), dim3(256), 0, stream, L, Lt16);
    hipLaunchKernelGGL(fused_kernel, dim3(NN / 4), dim3(256), 0, stream, I, A, T, Lt16, out);
}